// Round 6
// baseline (95.359 us; speedup 1.0000x reference)
//
#include <hip/hip_runtime.h>

#define HH 8
#define LL 4
#define PP 2
#define DD 32
#define CC 256
#define NVV 21760
#define NQQ 1000
#define BB 4
#define NQT (BB * NQQ)   // 4000 total queries

typedef __attribute__((ext_vector_type(8))) short short8;
typedef __attribute__((ext_vector_type(4))) short shortv4;
typedef __attribute__((ext_vector_type(4))) float f32x4;

__device__ __forceinline__ unsigned short f2bf(float f) {
    unsigned u = __float_as_uint(f);
    u += 0x7FFF + ((u >> 16) & 1);  // round-to-nearest-even
    return (unsigned short)(u >> 16);
}
__device__ __forceinline__ float bf2f(unsigned short h) {
    return __uint_as_float(((unsigned)h) << 16);
}
__device__ __forceinline__ unsigned cvtpk(float lo, float hi) {
    unsigned r;
    asm volatile("v_cvt_pk_bf16_f32 %0, %1, %2" : "=v"(r) : "v"(lo), "v"(hi));
    return r;
}

__device__ __forceinline__ void gload_lds16(const void* g, void* l) {
    __builtin_amdgcn_global_load_lds(
        (const __attribute__((address_space(1))) unsigned int*)g,
        (__attribute__((address_space(3))) unsigned int*)l, 16, 0, 0);
}

// ---------------------------------------------------------------------------
// Kernel 0: weight prep. Block c (=k row), thread n. Coalesced reads.
// Wslc: [half(n>>7)][slice(c>>5)][n&127][kk] bf16, XOR-swizzled within row:
//   byte addr (n7*64 + kk*2) ^= ((n7&3)<<4)   — baked source-side swizzle.
// W1T[n][c] = bf16([W_off|W_attn][c][n]),  WoT[n][c] = bf16(W_out[c][n])
// ---------------------------------------------------------------------------
__global__ __launch_bounds__(256) void prep_kernel(
    const float* __restrict__ Wv, const float* __restrict__ Woff,
    const float* __restrict__ Wattn, const float* __restrict__ Wout,
    unsigned short* __restrict__ Wslc, unsigned short* __restrict__ W1T,
    unsigned short* __restrict__ WoT)
{
    const int c = blockIdx.x;   // k index 0..255
    const int n = threadIdx.x;  // output col 0..255
    {
        int half = n >> 7, n7 = n & 127, s = c >> 5, kk = c & 31;
        unsigned addr = n7 * 64 + kk * 2;       // byte within 8KB slice plane
        addr ^= ((n7 & 3) << 4);                // bank swizzle
        Wslc[half * 32768 + s * 4096 + (addr >> 1)] = f2bf(Wv[c * CC + n]);
    }
    if (n < 192) {
        float x = (n < 128) ? Woff[c * 128 + n] : Wattn[c * 64 + (n - 128)];
        W1T[n * CC + c] = f2bf(x);
    }
    WoT[n * CC + c] = f2bf(Wout[c * CC + n]);
}

// ---------------------------------------------------------------------------
// Kernel 1: v[b*NVV+n][256] (bf16, ROW-MAJOR) = value @ W_val + b_val.
// BM=128, BN=128 (half of N per block; B-half = 64 KB LDS -> 2 blocks/CU).
// Grid 1360 = 680 m-tiles x 2 halves (interleaved for A reuse in L2/L3).
// 512 thr, 8 waves as 4M x 2N: wave owns 32 rows x 64 cols (2x4 fragments).
// Barrier-free K loop: B static in LDS; A depth-2 register pipeline with
// v_cvt_pk_bf16_f32 convert. Epilogue: LDS transpose -> packed b128 stores.
// ---------------------------------------------------------------------------
__global__ __launch_bounds__(512, 4) void valproj_mfma(
    const float* __restrict__ value, const unsigned short* __restrict__ Wslc,
    const float* __restrict__ bv, unsigned short* __restrict__ v_out)
{
    __shared__ __align__(16) unsigned short Bs[32768];  // 64 KB (reused as Cs)

    const int tid = threadIdx.x;
    const int w = tid >> 6;      // wave 0..7
    const int lane = tid & 63;
    const int wm = w >> 1;       // 0..3: 32-row M strip
    const int wn = w & 1;        // 0..1: 64-col N half (within block's 128)
    const int lr = lane & 15;
    const int q = lane >> 4;     // k-chunk / row-quad
    const int mt = blockIdx.x >> 1;
    const int hf = blockIdx.x & 1;     // which 128-col half of N=256
    const int bm = mt * 128;           // 680 m-tiles; NVV % 128 == 0

    // stage this half's B (64 KB) linearly into LDS, async
#pragma unroll
    for (int i = 0; i < 8; ++i) {
        size_t off = (size_t)i * 8192 + (size_t)tid * 16;  // bytes
        gload_lds16((const char*)Wslc + (size_t)hf * 65536 + off,
                    (char*)&Bs[0] + off);
    }
    __syncthreads();

    const float* arow0 = value + (size_t)(bm + wm * 32 + lr) * CC;

    float4 ab[2][2][2];  // [pipe][mf][lo/hi]
#define LOADA(p, s)                                                          \
    {                                                                        \
        _Pragma("unroll") for (int mf = 0; mf < 2; ++mf) {                   \
            const float* pp = arow0 + mf * 16 * CC + (s) * 32 + q * 8;       \
            ab[p][mf][0] = *(const float4*)pp;                               \
            ab[p][mf][1] = *(const float4*)(pp + 4);                         \
        }                                                                    \
    }

    LOADA(0, 0);
    LOADA(1, 1);

    f32x4 acc[2][4] = {};
#pragma unroll
    for (int s = 0; s < 8; ++s) {
        const int cur = s & 1;
        short8 af[2];
#pragma unroll
        for (int mf = 0; mf < 2; ++mf) {
            float4 f0 = ab[cur][mf][0], f1 = ab[cur][mf][1];
            uint4 uv = {cvtpk(f0.x, f0.y), cvtpk(f0.z, f0.w),
                        cvtpk(f1.x, f1.y), cvtpk(f1.z, f1.w)};
            af[mf] = __builtin_bit_cast(short8, uv);
        }
        if (s < 6) LOADA(cur, s + 2);
        short8 bfr[4];
#pragma unroll
        for (int nf = 0; nf < 4; ++nf) {
            int idx = s * 4096 +
                      (((wn * 64 + nf * 16 + lr) * 32 + q * 8) ^ ((lr & 3) << 3));
            bfr[nf] = *(const short8*)&Bs[idx];
        }
#pragma unroll
        for (int mf = 0; mf < 2; ++mf)
#pragma unroll
            for (int nf = 0; nf < 4; ++nf)
                acc[mf][nf] = __builtin_amdgcn_mfma_f32_16x16x32_bf16(
                    af[mf], bfr[nf], acc[mf][nf], 0, 0, 0);
    }
#undef LOADA

    // ---- epilogue: transpose through LDS, then packed 16B stores ----
    __syncthreads();  // all waves done reading Bs
    // C-tile staging: rows padded to 136 ushorts (272 B) to balance banks
#pragma unroll
    for (int nf = 0; nf < 4; ++nf) {
        int col = wn * 64 + nf * 16 + lr;
        float bias = bv[hf * 128 + col];
#pragma unroll
        for (int mf = 0; mf < 2; ++mf)
#pragma unroll
            for (int r = 0; r < 4; ++r) {
                int row = wm * 32 + mf * 16 + q * 4 + r;
                Bs[row * 136 + col] = f2bf(acc[mf][nf][r] + bias);
            }
    }
    __syncthreads();
    {
        int row = tid >> 2, ch = tid & 3;  // 128 rows x 4 x 64B chunks
        size_t obase = (size_t)(bm + row) * 256 + hf * 128 + ch * 32;
#pragma unroll
        for (int i = 0; i < 4; ++i) {
            short8 val = *(const short8*)&Bs[row * 136 + ch * 32 + i * 8];
            *(short8*)&v_out[obase + i * 8] = val;
        }
    }
}

// ---------------------------------------------------------------------------
// Kernel 2: logits[4000,192] = query @ [W_off|W_attn] + bias.
// BM=32, BK=64 (4 iters), 4 waves x 48 cols. Padded LDS rows (72).
// ---------------------------------------------------------------------------
__global__ __launch_bounds__(256) void logits_mfma(
    const float* __restrict__ query, const unsigned short* __restrict__ W1T,
    const float* __restrict__ b_off, const float* __restrict__ b_attn,
    float* __restrict__ logits)
{
    __shared__ unsigned short As[32][72];
    __shared__ unsigned short Bsl[192][72];
    const int tid = threadIdx.x;
    const int lane = tid & 63;
    const int wave = tid >> 6;
    const int bm = blockIdx.x * 32;  // 125 blocks * 32 = 4000
    const int lr = lane & 15;
    const int q = lane >> 4;
    f32x4 acc[2][3] = {};

    for (int k0 = 0; k0 < CC; k0 += 64) {
        float4 a[2];
        short8 wv[6];
#pragma unroll
        for (int i = 0; i < 2; ++i) {
            int u = tid + 256 * i;  // 512 float4 units: row=u>>4, col4=(u&15)*4
            a[i] = *(const float4*)&query[(size_t)(bm + (u >> 4)) * CC + k0 +
                                          (u & 15) * 4];
        }
#pragma unroll
        for (int i = 0; i < 6; ++i) {
            int u = tid + 256 * i;  // 1536 16B units: n=u>>3, j=u&7
            wv[i] = *(const short8*)&W1T[(size_t)(u >> 3) * CC + k0 + (u & 7) * 8];
        }
        __syncthreads();
#pragma unroll
        for (int i = 0; i < 2; ++i) {
            int u = tid + 256 * i;
            shortv4 p;
            p[0] = (short)f2bf(a[i].x); p[1] = (short)f2bf(a[i].y);
            p[2] = (short)f2bf(a[i].z); p[3] = (short)f2bf(a[i].w);
            *(shortv4*)&As[u >> 4][(u & 15) * 4] = p;
        }
#pragma unroll
        for (int i = 0; i < 6; ++i) {
            int u = tid + 256 * i;
            *(short8*)&Bsl[u >> 3][(u & 7) * 8] = wv[i];
        }
        __syncthreads();

#pragma unroll
        for (int kk = 0; kk < 2; ++kk) {
            short8 afr[2], bfr[3];
#pragma unroll
            for (int mf = 0; mf < 2; ++mf)
                afr[mf] = *(const short8*)&As[mf * 16 + lr][kk * 32 + q * 8];
#pragma unroll
            for (int nf = 0; nf < 3; ++nf)
                bfr[nf] =
                    *(const short8*)&Bsl[wave * 48 + nf * 16 + lr][kk * 32 + q * 8];
#pragma unroll
            for (int mf = 0; mf < 2; ++mf)
#pragma unroll
                for (int nf = 0; nf < 3; ++nf)
                    acc[mf][nf] = __builtin_amdgcn_mfma_f32_16x16x32_bf16(
                        afr[mf], bfr[nf], acc[mf][nf], 0, 0, 0);
        }
        __syncthreads();
    }

#pragma unroll
    for (int nf = 0; nf < 3; ++nf) {
        int col = wave * 48 + nf * 16 + lr;
        float bias = (col < 128) ? b_off[col] : b_attn[col - 128];
#pragma unroll
        for (int mf = 0; mf < 2; ++mf)
#pragma unroll
            for (int r = 0; r < 4; ++r) {
                int m = bm + mf * 16 + q * 4 + r;
                logits[(size_t)m * 192 + col] = acc[mf][nf][r] + bias;
            }
    }
}

// ---------------------------------------------------------------------------
// Kernel 3: sampling. One block per query (4000 blocks). Fuses softmax.
// v is ROW-MAJOR [b*NVV+n][256]; thread (h,d) gathers 8 samples x 4 corners.
// ---------------------------------------------------------------------------
__global__ __launch_bounds__(256) void sample_kernel(
    const float* __restrict__ logits,  // [4000][192]
    const float* __restrict__ refp,    // [B,NQ,L,2]
    const unsigned short* __restrict__ v,  // [B*NV][256] bf16
    unsigned short* __restrict__ mid)      // [4000][256] bf16
{
    __shared__ float offl[128];
    __shared__ float attnl[64];
    __shared__ float refl[8];

    const int qy = blockIdx.x;  // b*NQQ + nq
    const int b = qy / NQQ;
    const int tid = threadIdx.x;

    if (tid < 192) {
        float t = logits[(size_t)qy * 192 + tid];
        if (tid < 128) offl[tid] = t;
        else attnl[tid - 128] = t;
    } else if (tid < 200) {
        refl[tid - 192] = refp[(size_t)qy * 8 + (tid - 192)];
    }
    __syncthreads();

    if (tid < 8) {
        float m = -1e30f;
#pragma unroll
        for (int j = 0; j < 8; ++j) m = fmaxf(m, attnl[tid * 8 + j]);
        float s = 0.f, e[8];
#pragma unroll
        for (int j = 0; j < 8; ++j) {
            e[j] = __expf(attnl[tid * 8 + j] - m);
            s += e[j];
        }
        float inv = 1.f / s;
#pragma unroll
        for (int j = 0; j < 8; ++j) attnl[tid * 8 + j] = e[j] * inv;
    }
    __syncthreads();

    const int h = tid >> 5, d = tid & 31;
    const int starts[4] = {0, 16384, 20480, 21504};
    const float szs[4] = {128.f, 64.f, 32.f, 16.f};

    float acc = 0.f;
#pragma unroll
    for (int l = 0; l < LL; ++l) {
        const float S = szs[l];
        const int Wl = (int)S;
        const float refx = refl[l * 2 + 0];
        const float refy = refl[l * 2 + 1];
        const unsigned short* vl =
            v + (size_t)(b * NVV + starts[l]) * 256 + h * 32 + d;
#pragma unroll
        for (int p = 0; p < PP; ++p) {
            const int oi = h * 16 + l * 4 + p * 2;
            float lx = refx + offl[oi + 0] / S;
            float ly = refy + offl[oi + 1] / S;
            float x = lx * S - 0.5f;
            float y = ly * S - 0.5f;
            float x0f = floorf(x), y0f = floorf(y);
            float fx = x - x0f, fy = y - y0f;
            int x0 = (int)x0f, y0 = (int)y0f;
            float a = attnl[h * 8 + l * 2 + p];
            float sacc = 0.f;
#pragma unroll
            for (int dy = 0; dy < 2; ++dy) {
#pragma unroll
                for (int dx = 0; dx < 2; ++dx) {
                    int xi = x0 + dx, yi = y0 + dy;
                    float wgt = (dx ? fx : 1.f - fx) * (dy ? fy : 1.f - fy);
                    bool valid = (xi >= 0) && (xi < Wl) && (yi >= 0) && (yi < Wl);
                    int xc = min(max(xi, 0), Wl - 1);
                    int yc = min(max(yi, 0), Wl - 1);
                    float g = bf2f(vl[(size_t)(yc * Wl + xc) * 256]);
                    sacc += g * (valid ? wgt : 0.f);
                }
            }
            acc += a * sacc;
        }
    }
    mid[(size_t)qy * CC + h * 32 + d] = f2bf(acc);
}

// ---------------------------------------------------------------------------
// Kernel 4: out[4000,256] = mid_bf16 @ W_out_bf16 + b_out.
// BM=32, BK=64 (4 iters), 4 waves x 64 cols. Padded LDS rows (72).
// ---------------------------------------------------------------------------
__global__ __launch_bounds__(256) void out_mfma(
    const unsigned short* __restrict__ mid,
    const unsigned short* __restrict__ WoT, const float* __restrict__ b_out,
    float* __restrict__ out)
{
    __shared__ unsigned short As[32][72];
    __shared__ unsigned short Bso[256][72];
    const int tid = threadIdx.x;
    const int lane = tid & 63;
    const int wave = tid >> 6;
    const int bm = blockIdx.x * 32;
    const int lr = lane & 15;
    const int q = lane >> 4;
    f32x4 acc[2][4] = {};

    for (int k0 = 0; k0 < CC; k0 += 64) {
        short8 a0 = *(const short8*)&mid[(size_t)(bm + (tid >> 3)) * CC + k0 +
                                         (tid & 7) * 8];
        short8 wv[8];
#pragma unroll
        for (int i = 0; i < 8; ++i) {
            int u = tid + 256 * i;  // 2048 16B units: n=u>>3, j=u&7
            wv[i] = *(const short8*)&WoT[(size_t)(u >> 3) * CC + k0 + (u & 7) * 8];
        }
        __syncthreads();
        *(short8*)&As[tid >> 3][(tid & 7) * 8] = a0;
#pragma unroll
        for (int i = 0; i < 8; ++i) {
            int u = tid + 256 * i;
            *(short8*)&Bso[u >> 3][(u & 7) * 8] = wv[i];
        }
        __syncthreads();

#pragma unroll
        for (int kk = 0; kk < 2; ++kk) {
            short8 afr[2], bfr[4];
#pragma unroll
            for (int mf = 0; mf < 2; ++mf)
                afr[mf] = *(const short8*)&As[mf * 16 + lr][kk * 32 + q * 8];
#pragma unroll
            for (int nf = 0; nf < 4; ++nf)
                bfr[nf] =
                    *(const short8*)&Bso[wave * 64 + nf * 16 + lr][kk * 32 + q * 8];
#pragma unroll
            for (int mf = 0; mf < 2; ++mf)
#pragma unroll
                for (int nf = 0; nf < 4; ++nf)
                    acc[mf][nf] = __builtin_amdgcn_mfma_f32_16x16x32_bf16(
                        afr[mf], bfr[nf], acc[mf][nf], 0, 0, 0);
        }
        __syncthreads();
    }

#pragma unroll
    for (int nf = 0; nf < 4; ++nf) {
        int col = wave * 64 + nf * 16 + lr;
        float bias = b_out[col];
#pragma unroll
        for (int mf = 0; mf < 2; ++mf)
#pragma unroll
            for (int r = 0; r < 4; ++r) {
                int m = bm + mf * 16 + q * 4 + r;
                out[(size_t)m * CC + col] = acc[mf][nf][r] + bias;
            }
    }
}

extern "C" void kernel_launch(void* const* d_in, const int* in_sizes, int n_in,
                              void* d_out, int out_size, void* d_ws, size_t ws_size,
                              hipStream_t stream) {
    const float* query  = (const float*)d_in[0];
    const float* value  = (const float*)d_in[1];
    const float* refp   = (const float*)d_in[2];
    const float* W_off  = (const float*)d_in[3];
    const float* b_off  = (const float*)d_in[4];
    const float* W_attn = (const float*)d_in[5];
    const float* b_attn = (const float*)d_in[6];
    const float* W_val  = (const float*)d_in[7];
    const float* b_val  = (const float*)d_in[8];
    const float* W_out  = (const float*)d_in[9];
    const float* b_out  = (const float*)d_in[10];
    float* out = (float*)d_out;

    char* ws = (char*)d_ws;
    unsigned short* Wslc   = (unsigned short*)(ws);                  // 128 KB
    unsigned short* v_ws   = (unsigned short*)(ws + 131072);         // 44.56 MB
    unsigned short* W1T    = (unsigned short*)(ws + 44695552);       // 96 KB
    unsigned short* WoT    = (unsigned short*)(ws + 44793856);       // 128 KB
    float*          logits = (float*)(ws + 44924928);                // 3 MB
    unsigned short* mid    = (unsigned short*)(ws + 47996928);       // 2 MB

    prep_kernel<<<CC, 256, 0, stream>>>(W_val, W_off, W_attn, W_out,
                                        Wslc, W1T, WoT);
    valproj_mfma<<<(BB * NVV) / 128 * 2, 512, 0, stream>>>(value, Wslc, b_val,
                                                           v_ws);
    logits_mfma<<<NQT / 32, 256, 0, stream>>>(query, W1T, b_off, b_attn, logits);
    sample_kernel<<<NQT, 256, 0, stream>>>(logits, refp, v_ws, mid);
    out_mfma<<<NQT / 32, 256, 0, stream>>>(mid, WoT, b_out, out);
}

// Round 8
// 72.645 us; speedup vs baseline: 1.3127x; 1.3127x over previous
//
#include <hip/hip_runtime.h>

#define HH 8
#define LL 4
#define PP 2
#define DD 32
#define CC 256
#define NVV 21760
#define NQQ 1000
#define BB 4
#define NQT (BB * NQQ)   // 4000 total queries

typedef __attribute__((ext_vector_type(8))) short short8;
typedef __attribute__((ext_vector_type(4))) short shortv4;
typedef __attribute__((ext_vector_type(4))) float f32x4;

__device__ __forceinline__ unsigned short f2bf(float f) {
    unsigned u = __float_as_uint(f);
    u += 0x7FFF + ((u >> 16) & 1);  // round-to-nearest-even
    return (unsigned short)(u >> 16);
}
__device__ __forceinline__ float bf2f(unsigned short h) {
    return __uint_as_float(((unsigned)h) << 16);
}
__device__ __forceinline__ unsigned cvtpk(float lo, float hi) {
    unsigned r;
    asm volatile("v_cvt_pk_bf16_f32 %0, %1, %2" : "=v"(r) : "v"(lo), "v"(hi));
    return r;
}

__device__ __forceinline__ void gload_lds16(const void* g, void* l) {
    __builtin_amdgcn_global_load_lds(
        (const __attribute__((address_space(1))) unsigned int*)g,
        (__attribute__((address_space(3))) unsigned int*)l, 16, 0, 0);
}

// ---------------------------------------------------------------------------
// Kernel 0: weight prep. Block c (=k row, 0..255), thread n. Coalesced reads.
//  WTs: window-major [s=k>>5][n][32 k] bf16, XOR-baked so GEMM ds_read_b128
//       hits all 32 banks (2-way only): short idx = s*8192 + n*32 +
//       ((k&31) ^ (((n>>1)&3)<<3)).  Window = 16 KB contiguous -> the GEMM's
//       global_load_lds is a pure LINEAR copy (proven-safe pattern).
//  W1T[n][c] = bf16([W_off|W_attn][c][n]),  WoT[n][c] = bf16(W_out[c][n])
// ---------------------------------------------------------------------------
__global__ __launch_bounds__(256) void prep_kernel(
    const float* __restrict__ Wv, const float* __restrict__ Woff,
    const float* __restrict__ Wattn, const float* __restrict__ Wout,
    unsigned short* __restrict__ WTs, unsigned short* __restrict__ W1T,
    unsigned short* __restrict__ WoT)
{
    const int c = blockIdx.x;   // k index 0..255
    const int n = threadIdx.x;  // output col 0..255
    {
        int s = c >> 5, t = c & 31;
        WTs[s * 8192 + n * 32 + (t ^ (((n >> 1) & 3) << 3))] =
            f2bf(Wv[c * CC + n]);
    }
    if (n < 192) {
        float x = (n < 128) ? Woff[c * 128 + n] : Wattn[c * 64 + (n - 128)];
        W1T[n * CC + c] = f2bf(x);
    }
    WoT[n * CC + c] = f2bf(Wout[c * CC + n]);
}

// ---------------------------------------------------------------------------
// Kernel 1: v[b*NVV+n][256] (bf16, row-major) = value @ W_val + b_val.
// BM=64, BN=256, BK=32, 256 threads, 4 waves (2M x 2N; wave = 32 rows x 128
// cols = 2x8 fragments).  Proven mechanisms only:
//   A: direct global->VGPR float4 pairs, depth-1 prefetch. The per-iter
//      barrier's vmcnt(0) drain completes the prefetch AND stops the
//      compiler sinking it (R4-verified).
//   B: LINEAR global_load_lds copy of a 16 KB pre-swizzled window (prep
//      bakes the XOR); ds_read_b128 with the same XOR -> 2-way banks (free).
// LDS = 32 KB dbuf only -> target 4 blocks/CU (launch_bounds(256,4)).
// Epilogue: direct scalar stores (R4-proven, no write amplification).
// ---------------------------------------------------------------------------
__global__ __launch_bounds__(256, 4) void valproj_mfma(
    const float* __restrict__ value, const unsigned short* __restrict__ WTs,
    const float* __restrict__ bv, unsigned short* __restrict__ v_out)
{
    __shared__ __align__(16) char Bbuf[2][16384];

    const int tid = threadIdx.x;
    const int lane = tid & 63;
    const int w = tid >> 6;        // wave 0..3
    const int wm = w >> 1;         // 32-row strip
    const int wn = w & 1;          // 128-col half
    const int lr = lane & 15;
    const int q = lane >> 4;       // k-chunk / row-quad
    const int bm = blockIdx.x * 64;   // 1360 blocks; NVV % 64 == 0

    const float* arow0 = value + (size_t)(bm + wm * 32 + lr) * CC;

    // B window stage: pure linear copy (src offset == dest offset + const)
#define STAGEB(s, bi)                                                       \
    {                                                                       \
        _Pragma("unroll") for (int r = 0; r < 4; ++r) {                     \
            int off = (r * 256 + tid) * 16;                                 \
            gload_lds16((const char*)WTs + (s) * 16384 + off,               \
                        &Bbuf[bi][off]);                                    \
        }                                                                   \
    }
    // A fragment loads straight to VGPR (32B per lane per mf)
    float4 ab[2][2][2];  // [pipe][mf][lo/hi]
#define LOADA(s, p)                                                         \
    {                                                                       \
        _Pragma("unroll") for (int mf = 0; mf < 2; ++mf) {                  \
            const float* pp = arow0 + mf * 16 * CC + (s) * 32 + q * 8;      \
            ab[p][mf][0] = *(const float4*)pp;                              \
            ab[p][mf][1] = *(const float4*)(pp + 4);                        \
        }                                                                   \
    }

    f32x4 acc[2][8] = {};

    STAGEB(0, 0);
    LOADA(0, 0);
    __syncthreads();  // vmcnt(0): window 0 + A(0) resident

#pragma unroll
    for (int s = 0; s < 8; ++s) {
        const int cur = s & 1;
        if (s < 7) {
            STAGEB(s + 1, cur ^ 1);   // async DMA into other buffer
            LOADA(s + 1, cur ^ 1);    // prefetch next A into other pipe
        }
        short8 af[2];
#pragma unroll
        for (int mf = 0; mf < 2; ++mf) {
            float4 f0 = ab[cur][mf][0], f1 = ab[cur][mf][1];
            uint4 uv = {cvtpk(f0.x, f0.y), cvtpk(f0.z, f0.w),
                        cvtpk(f1.x, f1.y), cvtpk(f1.z, f1.w)};
            af[mf] = __builtin_bit_cast(short8, uv);
        }
#pragma unroll
        for (int nf = 0; nf < 8; ++nf) {
            int n = wn * 128 + nf * 16 + lr;
            short8 bf = *(const short8*)&Bbuf[cur][n * 64 +
                                                   ((q ^ ((n >> 1) & 3)) * 16)];
            acc[0][nf] = __builtin_amdgcn_mfma_f32_16x16x32_bf16(
                af[0], bf, acc[0][nf], 0, 0, 0);
            acc[1][nf] = __builtin_amdgcn_mfma_f32_16x16x32_bf16(
                af[1], bf, acc[1][nf], 0, 0, 0);
        }
        __syncthreads();  // drains next window's DMA + next A prefetch
    }
#undef STAGEB
#undef LOADA

    // epilogue: direct stores, v row-major [row][256]
#pragma unroll
    for (int nf = 0; nf < 8; ++nf) {
        int col = wn * 128 + nf * 16 + lr;
        float bias = bv[col];
#pragma unroll
        for (int mf = 0; mf < 2; ++mf) {
            size_t rbase = (size_t)(bm + wm * 32 + mf * 16 + q * 4) * 256 + col;
#pragma unroll
            for (int r = 0; r < 4; ++r)
                v_out[rbase + (size_t)r * 256] = f2bf(acc[mf][nf][r] + bias);
        }
    }
}

// ---------------------------------------------------------------------------
// Kernel 2: logits[4000,192] = query @ [W_off|W_attn] + bias.
// BM=32, BK=64 (4 iters), 4 waves x 48 cols. Padded LDS rows (72).
// ---------------------------------------------------------------------------
__global__ __launch_bounds__(256) void logits_mfma(
    const float* __restrict__ query, const unsigned short* __restrict__ W1T,
    const float* __restrict__ b_off, const float* __restrict__ b_attn,
    float* __restrict__ logits)
{
    __shared__ unsigned short As[32][72];
    __shared__ unsigned short Bsl[192][72];
    const int tid = threadIdx.x;
    const int lane = tid & 63;
    const int wave = tid >> 6;
    const int bm = blockIdx.x * 32;  // 125 blocks * 32 = 4000
    const int lr = lane & 15;
    const int q = lane >> 4;
    f32x4 acc[2][3] = {};

    for (int k0 = 0; k0 < CC; k0 += 64) {
        float4 a[2];
        short8 wv[6];
#pragma unroll
        for (int i = 0; i < 2; ++i) {
            int u = tid + 256 * i;  // 512 float4 units: row=u>>4, col4=(u&15)*4
            a[i] = *(const float4*)&query[(size_t)(bm + (u >> 4)) * CC + k0 +
                                          (u & 15) * 4];
        }
#pragma unroll
        for (int i = 0; i < 6; ++i) {
            int u = tid + 256 * i;  // 1536 16B units: n=u>>3, j=u&7
            wv[i] = *(const short8*)&W1T[(size_t)(u >> 3) * CC + k0 + (u & 7) * 8];
        }
        __syncthreads();
#pragma unroll
        for (int i = 0; i < 2; ++i) {
            int u = tid + 256 * i;
            shortv4 p;
            p[0] = (short)f2bf(a[i].x); p[1] = (short)f2bf(a[i].y);
            p[2] = (short)f2bf(a[i].z); p[3] = (short)f2bf(a[i].w);
            *(shortv4*)&As[u >> 4][(u & 15) * 4] = p;
        }
#pragma unroll
        for (int i = 0; i < 6; ++i) {
            int u = tid + 256 * i;
            *(short8*)&Bsl[u >> 3][(u & 7) * 8] = wv[i];
        }
        __syncthreads();

#pragma unroll
        for (int kk = 0; kk < 2; ++kk) {
            short8 afr[2], bfr[3];
#pragma unroll
            for (int mf = 0; mf < 2; ++mf)
                afr[mf] = *(const short8*)&As[mf * 16 + lr][kk * 32 + q * 8];
#pragma unroll
            for (int nf = 0; nf < 3; ++nf)
                bfr[nf] =
                    *(const short8*)&Bsl[wave * 48 + nf * 16 + lr][kk * 32 + q * 8];
#pragma unroll
            for (int mf = 0; mf < 2; ++mf)
#pragma unroll
                for (int nf = 0; nf < 3; ++nf)
                    acc[mf][nf] = __builtin_amdgcn_mfma_f32_16x16x32_bf16(
                        afr[mf], bfr[nf], acc[mf][nf], 0, 0, 0);
        }
        __syncthreads();
    }

#pragma unroll
    for (int nf = 0; nf < 3; ++nf) {
        int col = wave * 48 + nf * 16 + lr;
        float bias = (col < 128) ? b_off[col] : b_attn[col - 128];
#pragma unroll
        for (int mf = 0; mf < 2; ++mf)
#pragma unroll
            for (int r = 0; r < 4; ++r) {
                int m = bm + mf * 16 + q * 4 + r;
                logits[(size_t)m * 192 + col] = acc[mf][nf][r] + bias;
            }
    }
}

// ---------------------------------------------------------------------------
// Kernel 3: sampling. One block per query (4000 blocks). Fuses softmax.
// v is ROW-MAJOR [b*NVV+n][256]; thread (h,d) gathers 8 samples x 4 corners.
// ---------------------------------------------------------------------------
__global__ __launch_bounds__(256) void sample_kernel(
    const float* __restrict__ logits,  // [4000][192]
    const float* __restrict__ refp,    // [B,NQ,L,2]
    const unsigned short* __restrict__ v,  // [B*NV][256] bf16
    unsigned short* __restrict__ mid)      // [4000][256] bf16
{
    __shared__ float offl[128];
    __shared__ float attnl[64];
    __shared__ float refl[8];

    const int qy = blockIdx.x;  // b*NQQ + nq
    const int b = qy / NQQ;
    const int tid = threadIdx.x;

    if (tid < 192) {
        float t = logits[(size_t)qy * 192 + tid];
        if (tid < 128) offl[tid] = t;
        else attnl[tid - 128] = t;
    } else if (tid < 200) {
        refl[tid - 192] = refp[(size_t)qy * 8 + (tid - 192)];
    }
    __syncthreads();

    if (tid < 8) {
        float m = -1e30f;
#pragma unroll
        for (int j = 0; j < 8; ++j) m = fmaxf(m, attnl[tid * 8 + j]);
        float s = 0.f, e[8];
#pragma unroll
        for (int j = 0; j < 8; ++j) {
            e[j] = __expf(attnl[tid * 8 + j] - m);
            s += e[j];
        }
        float inv = 1.f / s;
#pragma unroll
        for (int j = 0; j < 8; ++j) attnl[tid * 8 + j] = e[j] * inv;
    }
    __syncthreads();

    const int h = tid >> 5, d = tid & 31;
    const int starts[4] = {0, 16384, 20480, 21504};
    const float szs[4] = {128.f, 64.f, 32.f, 16.f};

    float acc = 0.f;
#pragma unroll
    for (int l = 0; l < LL; ++l) {
        const float S = szs[l];
        const int Wl = (int)S;
        const float refx = refl[l * 2 + 0];
        const float refy = refl[l * 2 + 1];
        const unsigned short* vl =
            v + (size_t)(b * NVV + starts[l]) * 256 + h * 32 + d;
#pragma unroll
        for (int p = 0; p < PP; ++p) {
            const int oi = h * 16 + l * 4 + p * 2;
            float lx = refx + offl[oi + 0] / S;
            float ly = refy + offl[oi + 1] / S;
            float x = lx * S - 0.5f;
            float y = ly * S - 0.5f;
            float x0f = floorf(x), y0f = floorf(y);
            float fx = x - x0f, fy = y - y0f;
            int x0 = (int)x0f, y0 = (int)y0f;
            float a = attnl[h * 8 + l * 2 + p];
            float sacc = 0.f;
#pragma unroll
            for (int dy = 0; dy < 2; ++dy) {
#pragma unroll
                for (int dx = 0; dx < 2; ++dx) {
                    int xi = x0 + dx, yi = y0 + dy;
                    float wgt = (dx ? fx : 1.f - fx) * (dy ? fy : 1.f - fy);
                    bool valid = (xi >= 0) && (xi < Wl) && (yi >= 0) && (yi < Wl);
                    int xc = min(max(xi, 0), Wl - 1);
                    int yc = min(max(yi, 0), Wl - 1);
                    float g = bf2f(vl[(size_t)(yc * Wl + xc) * 256]);
                    sacc += g * (valid ? wgt : 0.f);
                }
            }
            acc += a * sacc;
        }
    }
    mid[(size_t)qy * CC + h * 32 + d] = f2bf(acc);
}

// ---------------------------------------------------------------------------
// Kernel 4: out[4000,256] = mid_bf16 @ W_out_bf16 + b_out.
// BM=32, BK=64 (4 iters), 4 waves x 64 cols. Padded LDS rows (72).
// ---------------------------------------------------------------------------
__global__ __launch_bounds__(256) void out_mfma(
    const unsigned short* __restrict__ mid,
    const unsigned short* __restrict__ WoT, const float* __restrict__ b_out,
    float* __restrict__ out)
{
    __shared__ unsigned short As[32][72];
    __shared__ unsigned short Bso[256][72];
    const int tid = threadIdx.x;
    const int lane = tid & 63;
    const int wave = tid >> 6;
    const int bm = blockIdx.x * 32;
    const int lr = lane & 15;
    const int q = lane >> 4;
    f32x4 acc[2][4] = {};

    for (int k0 = 0; k0 < CC; k0 += 64) {
        short8 a0 = *(const short8*)&mid[(size_t)(bm + (tid >> 3)) * CC + k0 +
                                         (tid & 7) * 8];
        short8 wv[8];
#pragma unroll
        for (int i = 0; i < 8; ++i) {
            int u = tid + 256 * i;  // 2048 16B units: n=u>>3, j=u&7
            wv[i] = *(const short8*)&WoT[(size_t)(u >> 3) * CC + k0 + (u & 7) * 8];
        }
        __syncthreads();
        *(short8*)&As[tid >> 3][(tid & 7) * 8] = a0;
#pragma unroll
        for (int i = 0; i < 8; ++i) {
            int u = tid + 256 * i;
            *(short8*)&Bso[u >> 3][(u & 7) * 8] = wv[i];
        }
        __syncthreads();

#pragma unroll
        for (int kk = 0; kk < 2; ++kk) {
            short8 afr[2], bfr[4];
#pragma unroll
            for (int mf = 0; mf < 2; ++mf)
                afr[mf] = *(const short8*)&As[mf * 16 + lr][kk * 32 + q * 8];
#pragma unroll
            for (int nf = 0; nf < 4; ++nf)
                bfr[nf] =
                    *(const short8*)&Bso[wave * 64 + nf * 16 + lr][kk * 32 + q * 8];
#pragma unroll
            for (int mf = 0; mf < 2; ++mf)
#pragma unroll
                for (int nf = 0; nf < 4; ++nf)
                    acc[mf][nf] = __builtin_amdgcn_mfma_f32_16x16x32_bf16(
                        afr[mf], bfr[nf], acc[mf][nf], 0, 0, 0);
        }
        __syncthreads();
    }

#pragma unroll
    for (int nf = 0; nf < 4; ++nf) {
        int col = wave * 64 + nf * 16 + lr;
        float bias = b_out[col];
#pragma unroll
        for (int mf = 0; mf < 2; ++mf)
#pragma unroll
            for (int r = 0; r < 4; ++r) {
                int m = bm + mf * 16 + q * 4 + r;
                out[(size_t)m * CC + col] = acc[mf][nf][r] + bias;
            }
    }
}

extern "C" void kernel_launch(void* const* d_in, const int* in_sizes, int n_in,
                              void* d_out, int out_size, void* d_ws, size_t ws_size,
                              hipStream_t stream) {
    const float* query  = (const float*)d_in[0];
    const float* value  = (const float*)d_in[1];
    const float* refp   = (const float*)d_in[2];
    const float* W_off  = (const float*)d_in[3];
    const float* b_off  = (const float*)d_in[4];
    const float* W_attn = (const float*)d_in[5];
    const float* b_attn = (const float*)d_in[6];
    const float* W_val  = (const float*)d_in[7];
    const float* b_val  = (const float*)d_in[8];
    const float* W_out  = (const float*)d_in[9];
    const float* b_out  = (const float*)d_in[10];
    float* out = (float*)d_out;

    char* ws = (char*)d_ws;
    unsigned short* WTs    = (unsigned short*)(ws);                  // 128 KB
    unsigned short* v_ws   = (unsigned short*)(ws + 131072);         // 44.56 MB
    unsigned short* W1T    = (unsigned short*)(ws + 44695552);       // 96 KB
    unsigned short* WoT    = (unsigned short*)(ws + 44793856);       // 128 KB
    float*          logits = (float*)(ws + 44924928);                // 3 MB
    unsigned short* mid    = (unsigned short*)(ws + 47996928);       // 2 MB

    prep_kernel<<<CC, 256, 0, stream>>>(W_val, W_off, W_attn, W_out,
                                        WTs, W1T, WoT);
    valproj_mfma<<<(BB * NVV) / 64, 256, 0, stream>>>(value, WTs, b_val, v_ws);
    logits_mfma<<<NQT / 32, 256, 0, stream>>>(query, W1T, b_off, b_attn, logits);
    sample_kernel<<<NQT, 256, 0, stream>>>(logits, refp, v_ws, mid);
    out_mfma<<<NQT / 32, 256, 0, stream>>>(mid, WoT, b_out, out);
}

// Round 9
// 63.842 us; speedup vs baseline: 1.4937x; 1.1379x over previous
//
#include <hip/hip_runtime.h>

#define HH 8
#define LL 4
#define PP 2
#define DD 32
#define CC 256
#define NVV 21760
#define NQQ 1000
#define BB 4
#define NQT (BB * NQQ)   // 4000 total queries

typedef __attribute__((ext_vector_type(8))) short short8;
typedef __attribute__((ext_vector_type(4))) short shortv4;
typedef __attribute__((ext_vector_type(4))) float f32x4;

__device__ __forceinline__ unsigned short f2bf(float f) {
    unsigned u = __float_as_uint(f);
    u += 0x7FFF + ((u >> 16) & 1);  // round-to-nearest-even
    return (unsigned short)(u >> 16);
}
__device__ __forceinline__ float bf2f(unsigned short h) {
    return __uint_as_float(((unsigned)h) << 16);
}
__device__ __forceinline__ unsigned cvtpk(float lo, float hi) {
    unsigned r;
    asm volatile("v_cvt_pk_bf16_f32 %0, %1, %2" : "=v"(r) : "v"(lo), "v"(hi));
    return r;
}

__device__ __forceinline__ void gload_lds16(const void* g, void* l) {
    __builtin_amdgcn_global_load_lds(
        (const __attribute__((address_space(1))) unsigned int*)g,
        (__attribute__((address_space(3))) unsigned int*)l, 16, 0, 0);
}

// ---------------------------------------------------------------------------
// Kernel 0: weight prep. Block c (=k row, 0..255), thread n. Coalesced reads.
//  WTs: window-major [s=k>>5][n][32 k] bf16, XOR-baked so GEMM ds_read_b128
//       hits all bank-quads evenly: short idx = s*8192 + n*32 +
//       ((k&31) ^ ((((n>>1)&3)<<3))).  Window = 16 KB contiguous -> GEMM's
//       global_load_lds is a pure LINEAR copy (R8-proven, 0 conflicts).
//  W1T[n][c] = bf16([W_off|W_attn][c][n]),  WoT[n][c] = bf16(W_out[c][n])
// ---------------------------------------------------------------------------
__global__ __launch_bounds__(256) void prep_kernel(
    const float* __restrict__ Wv, const float* __restrict__ Woff,
    const float* __restrict__ Wattn, const float* __restrict__ Wout,
    unsigned short* __restrict__ WTs, unsigned short* __restrict__ W1T,
    unsigned short* __restrict__ WoT)
{
    const int c = blockIdx.x;   // k index 0..255
    const int n = threadIdx.x;  // output col 0..255
    {
        int s = c >> 5, t = c & 31;
        WTs[s * 8192 + n * 32 + (t ^ (((n >> 1) & 3) << 3))] =
            f2bf(Wv[c * CC + n]);
    }
    if (n < 192) {
        float x = (n < 128) ? Woff[c * 128 + n] : Wattn[c * 64 + (n - 128)];
        W1T[n * CC + c] = f2bf(x);
    }
    WoT[n * CC + c] = f2bf(Wout[c * CC + n]);
}

// ---------------------------------------------------------------------------
// Kernel 1: v[b*NVV+n][256] (bf16, row-major) = value @ W_val + b_val.
// BM=64, BN=256, BK=32, 256 threads, 4 waves (2M x 2N).
// BOTH operands staged via global_load_lds (DMA is an LDS write -> the
// compiler CANNOT sink it past the barrier, unlike R8's VGPR A-prefetch
// which it provably sank: VGPR_Count=60 < the 96+ a held pipe needs).
//   A: per-lane swizzled SOURCE (chunk c holds k-chunk c^(m&7)), linear
//      wave-contiguous dest — verified algebra; R7's failure was its
//      epilogue stride (col<=255 written into 136-wide rows), NOT this.
//   B: linear copy of pre-swizzled 16 KB window (R8-proven, 0 conflicts).
// Double-buffered (48 KB -> 3 blocks/CU), ONE barrier per K-iter.
// Epilogue: direct scalar stores (R8-proven: WRITE_SIZE ~= ideal).
// ---------------------------------------------------------------------------
__global__ __launch_bounds__(256, 3) void valproj_mfma(
    const float* __restrict__ value, const unsigned short* __restrict__ WTs,
    const float* __restrict__ bv, unsigned short* __restrict__ v_out)
{
    __shared__ __align__(16) char Abuf[2][8192];    // [m][8 x 16B k-chunks]
    __shared__ __align__(16) char Bbuf[2][16384];   // [n][4 x 16B k-chunks]

    const int tid = threadIdx.x;
    const int lane = tid & 63;
    const int w = tid >> 6;        // wave 0..3
    const int wm = w >> 1;         // 32-row strip
    const int wn = w & 1;          // 128-col half
    const int lr = lane & 15;
    const int q = lane >> 4;       // k-chunk pair / row-quad
    const int bm = blockIdx.x * 64;   // 1360 blocks; NVV % 64 == 0

    // stage k-window s into buffer bi: all async DMA, barrier-ordered
#define STAGE(s, bi)                                                        \
    {                                                                       \
        _Pragma("unroll") for (int r = 0; r < 2; ++r) {                     \
            int u = r * 256 + tid;                                          \
            int m = u >> 3, c = u & 7;                                      \
            gload_lds16((const char*)value + (size_t)(bm + m) * 1024 +      \
                            (s) * 128 + ((c ^ (m & 7)) * 16),               \
                        &Abuf[bi][u * 16]);                                 \
        }                                                                   \
        _Pragma("unroll") for (int r = 0; r < 4; ++r) {                     \
            int off = (r * 256 + tid) * 16;                                 \
            gload_lds16((const char*)WTs + (s) * 16384 + off,               \
                        &Bbuf[bi][off]);                                    \
        }                                                                   \
    }

    f32x4 acc[2][8] = {};

    STAGE(0, 0);
    __syncthreads();  // vmcnt(0): window 0 resident

#pragma unroll
    for (int s = 0; s < 8; ++s) {
        const int cur = s & 1;
        if (s < 7) STAGE(s + 1, cur ^ 1);  // async DMA into other buffer

        short8 af[2];
#pragma unroll
        for (int mf = 0; mf < 2; ++mf) {
            int m = wm * 32 + mf * 16 + lr;
            const char* base = &Abuf[cur][m * 128];
            f32x4 lo = *(const f32x4*)(base + (((2 * q) ^ (m & 7)) * 16));
            f32x4 hi = *(const f32x4*)(base + (((2 * q + 1) ^ (m & 7)) * 16));
            uint4 uv = {cvtpk(lo[0], lo[1]), cvtpk(lo[2], lo[3]),
                        cvtpk(hi[0], hi[1]), cvtpk(hi[2], hi[3])};
            af[mf] = __builtin_bit_cast(short8, uv);
        }
#pragma unroll
        for (int nf = 0; nf < 8; ++nf) {
            int n = wn * 128 + nf * 16 + lr;
            short8 bf = *(const short8*)&Bbuf[cur][n * 64 +
                                                   ((q ^ ((n >> 1) & 3)) * 16)];
            acc[0][nf] = __builtin_amdgcn_mfma_f32_16x16x32_bf16(
                af[0], bf, acc[0][nf], 0, 0, 0);
            acc[1][nf] = __builtin_amdgcn_mfma_f32_16x16x32_bf16(
                af[1], bf, acc[1][nf], 0, 0, 0);
        }
        __syncthreads();  // next window's DMA drained + this buffer's reads done
    }
#undef STAGE

    // epilogue: direct stores, v row-major [row][256] (R8-proven)
#pragma unroll
    for (int nf = 0; nf < 8; ++nf) {
        int col = wn * 128 + nf * 16 + lr;
        float bias = bv[col];
#pragma unroll
        for (int mf = 0; mf < 2; ++mf) {
            size_t rbase = (size_t)(bm + wm * 32 + mf * 16 + q * 4) * 256 + col;
#pragma unroll
            for (int r = 0; r < 4; ++r)
                v_out[rbase + (size_t)r * 256] = f2bf(acc[mf][nf][r] + bias);
        }
    }
}

// ---------------------------------------------------------------------------
// Kernel 2: logits[4000,192] = query @ [W_off|W_attn] + bias.
// BM=32, BK=64 (4 iters), 4 waves x 48 cols. Padded LDS rows (72).
// ---------------------------------------------------------------------------
__global__ __launch_bounds__(256) void logits_mfma(
    const float* __restrict__ query, const unsigned short* __restrict__ W1T,
    const float* __restrict__ b_off, const float* __restrict__ b_attn,
    float* __restrict__ logits)
{
    __shared__ unsigned short As[32][72];
    __shared__ unsigned short Bsl[192][72];
    const int tid = threadIdx.x;
    const int lane = tid & 63;
    const int wave = tid >> 6;
    const int bm = blockIdx.x * 32;  // 125 blocks * 32 = 4000
    const int lr = lane & 15;
    const int q = lane >> 4;
    f32x4 acc[2][3] = {};

    for (int k0 = 0; k0 < CC; k0 += 64) {
        float4 a[2];
        short8 wv[6];
#pragma unroll
        for (int i = 0; i < 2; ++i) {
            int u = tid + 256 * i;  // 512 float4 units: row=u>>4, col4=(u&15)*4
            a[i] = *(const float4*)&query[(size_t)(bm + (u >> 4)) * CC + k0 +
                                          (u & 15) * 4];
        }
#pragma unroll
        for (int i = 0; i < 6; ++i) {
            int u = tid + 256 * i;  // 1536 16B units: n=u>>3, j=u&7
            wv[i] = *(const short8*)&W1T[(size_t)(u >> 3) * CC + k0 + (u & 7) * 8];
        }
        __syncthreads();
#pragma unroll
        for (int i = 0; i < 2; ++i) {
            int u = tid + 256 * i;
            shortv4 p;
            p[0] = (short)f2bf(a[i].x); p[1] = (short)f2bf(a[i].y);
            p[2] = (short)f2bf(a[i].z); p[3] = (short)f2bf(a[i].w);
            *(shortv4*)&As[u >> 4][(u & 15) * 4] = p;
        }
#pragma unroll
        for (int i = 0; i < 6; ++i) {
            int u = tid + 256 * i;
            *(short8*)&Bsl[u >> 3][(u & 7) * 8] = wv[i];
        }
        __syncthreads();

#pragma unroll
        for (int kk = 0; kk < 2; ++kk) {
            short8 afr[2], bfr[3];
#pragma unroll
            for (int mf = 0; mf < 2; ++mf)
                afr[mf] = *(const short8*)&As[mf * 16 + lr][kk * 32 + q * 8];
#pragma unroll
            for (int nf = 0; nf < 3; ++nf)
                bfr[nf] =
                    *(const short8*)&Bsl[wave * 48 + nf * 16 + lr][kk * 32 + q * 8];
#pragma unroll
            for (int mf = 0; mf < 2; ++mf)
#pragma unroll
                for (int nf = 0; nf < 3; ++nf)
                    acc[mf][nf] = __builtin_amdgcn_mfma_f32_16x16x32_bf16(
                        afr[mf], bfr[nf], acc[mf][nf], 0, 0, 0);
        }
        __syncthreads();
    }

#pragma unroll
    for (int nf = 0; nf < 3; ++nf) {
        int col = wave * 48 + nf * 16 + lr;
        float bias = (col < 128) ? b_off[col] : b_attn[col - 128];
#pragma unroll
        for (int mf = 0; mf < 2; ++mf)
#pragma unroll
            for (int r = 0; r < 4; ++r) {
                int m = bm + mf * 16 + q * 4 + r;
                logits[(size_t)m * 192 + col] = acc[mf][nf][r] + bias;
            }
    }
}

// ---------------------------------------------------------------------------
// Kernel 3: sampling. One block per query (4000 blocks). Fuses softmax.
// v is ROW-MAJOR [b*NVV+n][256]; thread (h,d) gathers 8 samples x 4 corners.
// ---------------------------------------------------------------------------
__global__ __launch_bounds__(256) void sample_kernel(
    const float* __restrict__ logits,  // [4000][192]
    const float* __restrict__ refp,    // [B,NQ,L,2]
    const unsigned short* __restrict__ v,  // [B*NV][256] bf16
    unsigned short* __restrict__ mid)      // [4000][256] bf16
{
    __shared__ float offl[128];
    __shared__ float attnl[64];
    __shared__ float refl[8];

    const int qy = blockIdx.x;  // b*NQQ + nq
    const int b = qy / NQQ;
    const int tid = threadIdx.x;

    if (tid < 192) {
        float t = logits[(size_t)qy * 192 + tid];
        if (tid < 128) offl[tid] = t;
        else attnl[tid - 128] = t;
    } else if (tid < 200) {
        refl[tid - 192] = refp[(size_t)qy * 8 + (tid - 192)];
    }
    __syncthreads();

    if (tid < 8) {
        float m = -1e30f;
#pragma unroll
        for (int j = 0; j < 8; ++j) m = fmaxf(m, attnl[tid * 8 + j]);
        float s = 0.f, e[8];
#pragma unroll
        for (int j = 0; j < 8; ++j) {
            e[j] = __expf(attnl[tid * 8 + j] - m);
            s += e[j];
        }
        float inv = 1.f / s;
#pragma unroll
        for (int j = 0; j < 8; ++j) attnl[tid * 8 + j] = e[j] * inv;
    }
    __syncthreads();

    const int h = tid >> 5, d = tid & 31;
    const int starts[4] = {0, 16384, 20480, 21504};
    const float szs[4] = {128.f, 64.f, 32.f, 16.f};

    float acc = 0.f;
#pragma unroll
    for (int l = 0; l < LL; ++l) {
        const float S = szs[l];
        const int Wl = (int)S;
        const float refx = refl[l * 2 + 0];
        const float refy = refl[l * 2 + 1];
        const unsigned short* vl =
            v + (size_t)(b * NVV + starts[l]) * 256 + h * 32 + d;
#pragma unroll
        for (int p = 0; p < PP; ++p) {
            const int oi = h * 16 + l * 4 + p * 2;
            float lx = refx + offl[oi + 0] / S;
            float ly = refy + offl[oi + 1] / S;
            float x = lx * S - 0.5f;
            float y = ly * S - 0.5f;
            float x0f = floorf(x), y0f = floorf(y);
            float fx = x - x0f, fy = y - y0f;
            int x0 = (int)x0f, y0 = (int)y0f;
            float a = attnl[h * 8 + l * 2 + p];
            float sacc = 0.f;
#pragma unroll
            for (int dy = 0; dy < 2; ++dy) {
#pragma unroll
                for (int dx = 0; dx < 2; ++dx) {
                    int xi = x0 + dx, yi = y0 + dy;
                    float wgt = (dx ? fx : 1.f - fx) * (dy ? fy : 1.f - fy);
                    bool valid = (xi >= 0) && (xi < Wl) && (yi >= 0) && (yi < Wl);
                    int xc = min(max(xi, 0), Wl - 1);
                    int yc = min(max(yi, 0), Wl - 1);
                    float g = bf2f(vl[(size_t)(yc * Wl + xc) * 256]);
                    sacc += g * (valid ? wgt : 0.f);
                }
            }
            acc += a * sacc;
        }
    }
    mid[(size_t)qy * CC + h * 32 + d] = f2bf(acc);
}

// ---------------------------------------------------------------------------
// Kernel 4: out[4000,256] = mid_bf16 @ W_out_bf16 + b_out.
// BM=32, BK=64 (4 iters), 4 waves x 64 cols. Padded LDS rows (72).
// ---------------------------------------------------------------------------
__global__ __launch_bounds__(256) void out_mfma(
    const unsigned short* __restrict__ mid,
    const unsigned short* __restrict__ WoT, const float* __restrict__ b_out,
    float* __restrict__ out)
{
    __shared__ unsigned short As[32][72];
    __shared__ unsigned short Bso[256][72];
    const int tid = threadIdx.x;
    const int lane = tid & 63;
    const int wave = tid >> 6;
    const int bm = blockIdx.x * 32;
    const int lr = lane & 15;
    const int q = lane >> 4;
    f32x4 acc[2][4] = {};

    for (int k0 = 0; k0 < CC; k0 += 64) {
        short8 a0 = *(const short8*)&mid[(size_t)(bm + (tid >> 3)) * CC + k0 +
                                         (tid & 7) * 8];
        short8 wv[8];
#pragma unroll
        for (int i = 0; i < 8; ++i) {
            int u = tid + 256 * i;  // 2048 16B units: n=u>>3, j=u&7
            wv[i] = *(const short8*)&WoT[(size_t)(u >> 3) * CC + k0 + (u & 7) * 8];
        }
        __syncthreads();
        *(short8*)&As[tid >> 3][(tid & 7) * 8] = a0;
#pragma unroll
        for (int i = 0; i < 8; ++i) {
            int u = tid + 256 * i;
            *(short8*)&Bso[u >> 3][(u & 7) * 8] = wv[i];
        }
        __syncthreads();

#pragma unroll
        for (int kk = 0; kk < 2; ++kk) {
            short8 afr[2], bfr[4];
#pragma unroll
            for (int mf = 0; mf < 2; ++mf)
                afr[mf] = *(const short8*)&As[mf * 16 + lr][kk * 32 + q * 8];
#pragma unroll
            for (int nf = 0; nf < 4; ++nf)
                bfr[nf] =
                    *(const short8*)&Bso[wave * 64 + nf * 16 + lr][kk * 32 + q * 8];
#pragma unroll
            for (int mf = 0; mf < 2; ++mf)
#pragma unroll
                for (int nf = 0; nf < 4; ++nf)
                    acc[mf][nf] = __builtin_amdgcn_mfma_f32_16x16x32_bf16(
                        afr[mf], bfr[nf], acc[mf][nf], 0, 0, 0);
        }
        __syncthreads();
    }

#pragma unroll
    for (int nf = 0; nf < 4; ++nf) {
        int col = wave * 64 + nf * 16 + lr;
        float bias = b_out[col];
#pragma unroll
        for (int mf = 0; mf < 2; ++mf)
#pragma unroll
            for (int r = 0; r < 4; ++r) {
                int m = bm + mf * 16 + q * 4 + r;
                out[(size_t)m * CC + col] = acc[mf][nf][r] + bias;
            }
    }
}

extern "C" void kernel_launch(void* const* d_in, const int* in_sizes, int n_in,
                              void* d_out, int out_size, void* d_ws, size_t ws_size,
                              hipStream_t stream) {
    const float* query  = (const float*)d_in[0];
    const float* value  = (const float*)d_in[1];
    const float* refp   = (const float*)d_in[2];
    const float* W_off  = (const float*)d_in[3];
    const float* b_off  = (const float*)d_in[4];
    const float* W_attn = (const float*)d_in[5];
    const float* b_attn = (const float*)d_in[6];
    const float* W_val  = (const float*)d_in[7];
    const float* b_val  = (const float*)d_in[8];
    const float* W_out  = (const float*)d_in[9];
    const float* b_out  = (const float*)d_in[10];
    float* out = (float*)d_out;

    char* ws = (char*)d_ws;
    unsigned short* WTs    = (unsigned short*)(ws);                  // 128 KB
    unsigned short* v_ws   = (unsigned short*)(ws + 131072);         // 44.56 MB
    unsigned short* W1T    = (unsigned short*)(ws + 44695552);       // 96 KB
    unsigned short* WoT    = (unsigned short*)(ws + 44793856);       // 128 KB
    float*          logits = (float*)(ws + 44924928);                // 3 MB
    unsigned short* mid    = (unsigned short*)(ws + 47996928);       // 2 MB

    prep_kernel<<<CC, 256, 0, stream>>>(W_val, W_off, W_attn, W_out,
                                        WTs, W1T, WoT);
    valproj_mfma<<<(BB * NVV) / 64, 256, 0, stream>>>(value, WTs, b_val, v_ws);
    logits_mfma<<<NQT / 32, 256, 0, stream>>>(query, W1T, b_off, b_attn, logits);
    sample_kernel<<<NQT, 256, 0, stream>>>(logits, refp, v_ws, mid);
    out_mfma<<<NQT / 32, 256, 0, stream>>>(mid, WoT, b_out, out);
}

// Round 10
// 62.613 us; speedup vs baseline: 1.5230x; 1.0196x over previous
//
#include <hip/hip_runtime.h>

#define HH 8
#define LL 4
#define PP 2
#define DD 32
#define CC 256
#define NVV 21760
#define NQQ 1000
#define BB 4
#define NQT (BB * NQQ)   // 4000 total queries

typedef __attribute__((ext_vector_type(8))) short short8;
typedef __attribute__((ext_vector_type(4))) short shortv4;
typedef __attribute__((ext_vector_type(4))) float f32x4;

__device__ __forceinline__ unsigned short f2bf(float f) {
    unsigned u = __float_as_uint(f);
    u += 0x7FFF + ((u >> 16) & 1);  // round-to-nearest-even
    return (unsigned short)(u >> 16);
}
__device__ __forceinline__ float bf2f(unsigned short h) {
    return __uint_as_float(((unsigned)h) << 16);
}
__device__ __forceinline__ unsigned cvtpk(float lo, float hi) {
    unsigned r;
    asm volatile("v_cvt_pk_bf16_f32 %0, %1, %2" : "=v"(r) : "v"(lo), "v"(hi));
    return r;
}

__device__ __forceinline__ void gload_lds16(const void* g, void* l) {
    __builtin_amdgcn_global_load_lds(
        (const __attribute__((address_space(1))) unsigned int*)g,
        (__attribute__((address_space(3))) unsigned int*)l, 16, 0, 0);
}

// ---------------------------------------------------------------------------
// Kernel 0: weight prep. Block c (=k row, 0..255), thread n. Coalesced reads.
//  WTs: window-major [s=k>>5][n][32 k] bf16, XOR-baked (R8/R9-proven:
//       0 LDS bank conflicts). Window = 16 KB contiguous -> linear DMA.
//  W1T[n][c] = bf16([W_off|W_attn][c][n]),  WoT[n][c] = bf16(W_out[c][n])
// ---------------------------------------------------------------------------
__global__ __launch_bounds__(256) void prep_kernel(
    const float* __restrict__ Wv, const float* __restrict__ Woff,
    const float* __restrict__ Wattn, const float* __restrict__ Wout,
    unsigned short* __restrict__ WTs, unsigned short* __restrict__ W1T,
    unsigned short* __restrict__ WoT)
{
    const int c = blockIdx.x;   // k index 0..255
    const int n = threadIdx.x;  // output col 0..255
    {
        int s = c >> 5, t = c & 31;
        WTs[s * 8192 + n * 32 + (t ^ (((n >> 1) & 3) << 3))] =
            f2bf(Wv[c * CC + n]);
    }
    if (n < 192) {
        float x = (n < 128) ? Woff[c * 128 + n] : Wattn[c * 64 + (n - 128)];
        W1T[n * CC + c] = f2bf(x);
    }
    WoT[n * CC + c] = f2bf(Wout[c * CC + n]);
}

// ---------------------------------------------------------------------------
// Kernel 1: v[b*NVV+n][256] (bf16, row-major) = value @ W_val + b_val.
// R9 structure (both operands via global_load_lds DMA, verified correct,
// 0 conflicts) + T3/T4 counted-vmcnt barriers (replaces __syncthreads whose
// mandatory vmcnt(0) drain serialized every K-iter on a full HBM round trip):
//   iter s:  s_waitcnt vmcnt(6)   // own window-s DMAs landed; window s+1
//            s_barrier             // may stay IN FLIGHT across the barrier
//            sched_barrier(0)      // rule-18 anti-hoist fence
//            ds_read + cvt_pk + 16 MFMA
//            s_barrier; sched_barrier(0)
//            STAGE(s+2)            // refill the buffer just consumed
// Per-thread vmem ops in the loop = exactly 6 DMA/STAGE, so counts are exact.
// ---------------------------------------------------------------------------
__global__ __launch_bounds__(256, 3) void valproj_mfma(
    const float* __restrict__ value, const unsigned short* __restrict__ WTs,
    const float* __restrict__ bv, unsigned short* __restrict__ v_out)
{
    __shared__ __align__(16) char Abuf[2][8192];    // [m][8 x 16B k-chunks]
    __shared__ __align__(16) char Bbuf[2][16384];   // [n][4 x 16B k-chunks]

    const int tid = threadIdx.x;
    const int lane = tid & 63;
    const int w = tid >> 6;        // wave 0..3
    const int wm = w >> 1;         // 32-row strip
    const int wn = w & 1;          // 128-col half
    const int lr = lane & 15;
    const int q = lane >> 4;       // k-chunk pair / row-quad
    const int bm = blockIdx.x * 64;   // 1360 blocks; NVV % 64 == 0

    // stage k-window s into buffer bi: async DMA (A: swizzled source, linear
    // dest; B: pure linear copy of pre-swizzled window) — R9-proven.
#define STAGE(s, bi)                                                        \
    {                                                                       \
        _Pragma("unroll") for (int r = 0; r < 2; ++r) {                     \
            int u = r * 256 + tid;                                          \
            int m = u >> 3, c = u & 7;                                      \
            gload_lds16((const char*)value + (size_t)(bm + m) * 1024 +      \
                            (s) * 128 + ((c ^ (m & 7)) * 16),               \
                        &Abuf[bi][u * 16]);                                 \
        }                                                                   \
        _Pragma("unroll") for (int r = 0; r < 4; ++r) {                     \
            int off = (r * 256 + tid) * 16;                                 \
            gload_lds16((const char*)WTs + (s) * 16384 + off,               \
                        &Bbuf[bi][off]);                                    \
        }                                                                   \
    }

    f32x4 acc[2][8] = {};

    STAGE(0, 0);
    STAGE(1, 1);   // 12 DMA outstanding per thread

#pragma unroll
    for (int s = 0; s < 8; ++s) {
        const int cur = s & 1;
        // wait for OUR window-s loads; window s+1's 6 may remain in flight
        if (s < 7) {
            asm volatile("s_waitcnt vmcnt(6)" ::: "memory");
        } else {
            asm volatile("s_waitcnt vmcnt(0)" ::: "memory");
        }
        __builtin_amdgcn_s_barrier();      // everyone's window-s DMAs landed
        __builtin_amdgcn_sched_barrier(0); // nothing hoists above the wait

        short8 af[2];
#pragma unroll
        for (int mf = 0; mf < 2; ++mf) {
            int m = wm * 32 + mf * 16 + lr;
            const char* base = &Abuf[cur][m * 128];
            f32x4 lo = *(const f32x4*)(base + (((2 * q) ^ (m & 7)) * 16));
            f32x4 hi = *(const f32x4*)(base + (((2 * q + 1) ^ (m & 7)) * 16));
            uint4 uv = {cvtpk(lo[0], lo[1]), cvtpk(lo[2], lo[3]),
                        cvtpk(hi[0], hi[1]), cvtpk(hi[2], hi[3])};
            af[mf] = __builtin_bit_cast(short8, uv);
        }
#pragma unroll
        for (int nf = 0; nf < 8; ++nf) {
            int n = wn * 128 + nf * 16 + lr;
            short8 bf = *(const short8*)&Bbuf[cur][n * 64 +
                                                   ((q ^ ((n >> 1) & 3)) * 16)];
            acc[0][nf] = __builtin_amdgcn_mfma_f32_16x16x32_bf16(
                af[0], bf, acc[0][nf], 0, 0, 0);
            acc[1][nf] = __builtin_amdgcn_mfma_f32_16x16x32_bf16(
                af[1], bf, acc[1][nf], 0, 0, 0);
        }

        __builtin_amdgcn_s_barrier();      // all waves done reading buf[cur]
        __builtin_amdgcn_sched_barrier(0); // STAGE stays below the barrier
        if (s < 6) STAGE(s + 2, cur);      // refill consumed buffer
    }
#undef STAGE

    // epilogue: direct stores, v row-major [row][256] (R8/R9-proven)
#pragma unroll
    for (int nf = 0; nf < 8; ++nf) {
        int col = wn * 128 + nf * 16 + lr;
        float bias = bv[col];
#pragma unroll
        for (int mf = 0; mf < 2; ++mf) {
            size_t rbase = (size_t)(bm + wm * 32 + mf * 16 + q * 4) * 256 + col;
#pragma unroll
            for (int r = 0; r < 4; ++r)
                v_out[rbase + (size_t)r * 256] = f2bf(acc[mf][nf][r] + bias);
        }
    }
}

// ---------------------------------------------------------------------------
// Kernel 2: logits[4000,192] = query @ [W_off|W_attn] + bias.
// BM=32, BK=64 (4 iters), 4 waves x 48 cols. Padded LDS rows (72).
// ---------------------------------------------------------------------------
__global__ __launch_bounds__(256) void logits_mfma(
    const float* __restrict__ query, const unsigned short* __restrict__ W1T,
    const float* __restrict__ b_off, const float* __restrict__ b_attn,
    float* __restrict__ logits)
{
    __shared__ unsigned short As[32][72];
    __shared__ unsigned short Bsl[192][72];
    const int tid = threadIdx.x;
    const int lane = tid & 63;
    const int wave = tid >> 6;
    const int bm = blockIdx.x * 32;  // 125 blocks * 32 = 4000
    const int lr = lane & 15;
    const int q = lane >> 4;
    f32x4 acc[2][3] = {};

    for (int k0 = 0; k0 < CC; k0 += 64) {
        float4 a[2];
        short8 wv[6];
#pragma unroll
        for (int i = 0; i < 2; ++i) {
            int u = tid + 256 * i;  // 512 float4 units: row=u>>4, col4=(u&15)*4
            a[i] = *(const float4*)&query[(size_t)(bm + (u >> 4)) * CC + k0 +
                                          (u & 15) * 4];
        }
#pragma unroll
        for (int i = 0; i < 6; ++i) {
            int u = tid + 256 * i;  // 1536 16B units: n=u>>3, j=u&7
            wv[i] = *(const short8*)&W1T[(size_t)(u >> 3) * CC + k0 + (u & 7) * 8];
        }
        __syncthreads();
#pragma unroll
        for (int i = 0; i < 2; ++i) {
            int u = tid + 256 * i;
            shortv4 p;
            p[0] = (short)f2bf(a[i].x); p[1] = (short)f2bf(a[i].y);
            p[2] = (short)f2bf(a[i].z); p[3] = (short)f2bf(a[i].w);
            *(shortv4*)&As[u >> 4][(u & 15) * 4] = p;
        }
#pragma unroll
        for (int i = 0; i < 6; ++i) {
            int u = tid + 256 * i;
            *(short8*)&Bsl[u >> 3][(u & 7) * 8] = wv[i];
        }
        __syncthreads();

#pragma unroll
        for (int kk = 0; kk < 2; ++kk) {
            short8 afr[2], bfr[3];
#pragma unroll
            for (int mf = 0; mf < 2; ++mf)
                afr[mf] = *(const short8*)&As[mf * 16 + lr][kk * 32 + q * 8];
#pragma unroll
            for (int nf = 0; nf < 3; ++nf)
                bfr[nf] =
                    *(const short8*)&Bsl[wave * 48 + nf * 16 + lr][kk * 32 + q * 8];
#pragma unroll
            for (int mf = 0; mf < 2; ++mf)
#pragma unroll
                for (int nf = 0; nf < 3; ++nf)
                    acc[mf][nf] = __builtin_amdgcn_mfma_f32_16x16x32_bf16(
                        afr[mf], bfr[nf], acc[mf][nf], 0, 0, 0);
        }
        __syncthreads();
    }

#pragma unroll
    for (int nf = 0; nf < 3; ++nf) {
        int col = wave * 48 + nf * 16 + lr;
        float bias = (col < 128) ? b_off[col] : b_attn[col - 128];
#pragma unroll
        for (int mf = 0; mf < 2; ++mf)
#pragma unroll
            for (int r = 0; r < 4; ++r) {
                int m = bm + mf * 16 + q * 4 + r;
                logits[(size_t)m * 192 + col] = acc[mf][nf][r] + bias;
            }
    }
}

// ---------------------------------------------------------------------------
// Kernel 3: sampling. One block per query (4000 blocks). Fuses softmax.
// v is ROW-MAJOR [b*NVV+n][256]; thread (h,d) gathers 8 samples x 4 corners.
// ---------------------------------------------------------------------------
__global__ __launch_bounds__(256) void sample_kernel(
    const float* __restrict__ logits,  // [4000][192]
    const float* __restrict__ refp,    // [B,NQ,L,2]
    const unsigned short* __restrict__ v,  // [B*NV][256] bf16
    unsigned short* __restrict__ mid)      // [4000][256] bf16
{
    __shared__ float offl[128];
    __shared__ float attnl[64];
    __shared__ float refl[8];

    const int qy = blockIdx.x;  // b*NQQ + nq
    const int b = qy / NQQ;
    const int tid = threadIdx.x;

    if (tid < 192) {
        float t = logits[(size_t)qy * 192 + tid];
        if (tid < 128) offl[tid] = t;
        else attnl[tid - 128] = t;
    } else if (tid < 200) {
        refl[tid - 192] = refp[(size_t)qy * 8 + (tid - 192)];
    }
    __syncthreads();

    if (tid < 8) {
        float m = -1e30f;
#pragma unroll
        for (int j = 0; j < 8; ++j) m = fmaxf(m, attnl[tid * 8 + j]);
        float s = 0.f, e[8];
#pragma unroll
        for (int j = 0; j < 8; ++j) {
            e[j] = __expf(attnl[tid * 8 + j] - m);
            s += e[j];
        }
        float inv = 1.f / s;
#pragma unroll
        for (int j = 0; j < 8; ++j) attnl[tid * 8 + j] = e[j] * inv;
    }
    __syncthreads();

    const int h = tid >> 5, d = tid & 31;
    const int starts[4] = {0, 16384, 20480, 21504};
    const float szs[4] = {128.f, 64.f, 32.f, 16.f};

    float acc = 0.f;
#pragma unroll
    for (int l = 0; l < LL; ++l) {
        const float S = szs[l];
        const int Wl = (int)S;
        const float refx = refl[l * 2 + 0];
        const float refy = refl[l * 2 + 1];
        const unsigned short* vl =
            v + (size_t)(b * NVV + starts[l]) * 256 + h * 32 + d;
#pragma unroll
        for (int p = 0; p < PP; ++p) {
            const int oi = h * 16 + l * 4 + p * 2;
            float lx = refx + offl[oi + 0] / S;
            float ly = refy + offl[oi + 1] / S;
            float x = lx * S - 0.5f;
            float y = ly * S - 0.5f;
            float x0f = floorf(x), y0f = floorf(y);
            float fx = x - x0f, fy = y - y0f;
            int x0 = (int)x0f, y0 = (int)y0f;
            float a = attnl[h * 8 + l * 2 + p];
            float sacc = 0.f;
#pragma unroll
            for (int dy = 0; dy < 2; ++dy) {
#pragma unroll
                for (int dx = 0; dx < 2; ++dx) {
                    int xi = x0 + dx, yi = y0 + dy;
                    float wgt = (dx ? fx : 1.f - fx) * (dy ? fy : 1.f - fy);
                    bool valid = (xi >= 0) && (xi < Wl) && (yi >= 0) && (yi < Wl);
                    int xc = min(max(xi, 0), Wl - 1);
                    int yc = min(max(yi, 0), Wl - 1);
                    float g = bf2f(vl[(size_t)(yc * Wl + xc) * 256]);
                    sacc += g * (valid ? wgt : 0.f);
                }
            }
            acc += a * sacc;
        }
    }
    mid[(size_t)qy * CC + h * 32 + d] = f2bf(acc);
}

// ---------------------------------------------------------------------------
// Kernel 4: out[4000,256] = mid_bf16 @ W_out_bf16 + b_out.
// BM=32, BK=64 (4 iters), 4 waves x 64 cols. Padded LDS rows (72).
// ---------------------------------------------------------------------------
__global__ __launch_bounds__(256) void out_mfma(
    const unsigned short* __restrict__ mid,
    const unsigned short* __restrict__ WoT, const float* __restrict__ b_out,
    float* __restrict__ out)
{
    __shared__ unsigned short As[32][72];
    __shared__ unsigned short Bso[256][72];
    const int tid = threadIdx.x;
    const int lane = tid & 63;
    const int wave = tid >> 6;
    const int bm = blockIdx.x * 32;
    const int lr = lane & 15;
    const int q = lane >> 4;
    f32x4 acc[2][4] = {};

    for (int k0 = 0; k0 < CC; k0 += 64) {
        short8 a0 = *(const short8*)&mid[(size_t)(bm + (tid >> 3)) * CC + k0 +
                                         (tid & 7) * 8];
        short8 wv[8];
#pragma unroll
        for (int i = 0; i < 8; ++i) {
            int u = tid + 256 * i;  // 2048 16B units: n=u>>3, j=u&7
            wv[i] = *(const short8*)&WoT[(size_t)(u >> 3) * CC + k0 + (u & 7) * 8];
        }
        __syncthreads();
        *(short8*)&As[tid >> 3][(tid & 7) * 8] = a0;
#pragma unroll
        for (int i = 0; i < 8; ++i) {
            int u = tid + 256 * i;
            *(short8*)&Bso[u >> 3][(u & 7) * 8] = wv[i];
        }
        __syncthreads();

#pragma unroll
        for (int kk = 0; kk < 2; ++kk) {
            short8 afr[2], bfr[4];
#pragma unroll
            for (int mf = 0; mf < 2; ++mf)
                afr[mf] = *(const short8*)&As[mf * 16 + lr][kk * 32 + q * 8];
#pragma unroll
            for (int nf = 0; nf < 4; ++nf)
                bfr[nf] =
                    *(const short8*)&Bso[wave * 64 + nf * 16 + lr][kk * 32 + q * 8];
#pragma unroll
            for (int mf = 0; mf < 2; ++mf)
#pragma unroll
                for (int nf = 0; nf < 4; ++nf)
                    acc[mf][nf] = __builtin_amdgcn_mfma_f32_16x16x32_bf16(
                        afr[mf], bfr[nf], acc[mf][nf], 0, 0, 0);
        }
        __syncthreads();
    }

#pragma unroll
    for (int nf = 0; nf < 4; ++nf) {
        int col = wave * 64 + nf * 16 + lr;
        float bias = b_out[col];
#pragma unroll
        for (int mf = 0; mf < 2; ++mf)
#pragma unroll
            for (int r = 0; r < 4; ++r) {
                int m = bm + mf * 16 + q * 4 + r;
                out[(size_t)m * CC + col] = acc[mf][nf][r] + bias;
            }
    }
}

extern "C" void kernel_launch(void* const* d_in, const int* in_sizes, int n_in,
                              void* d_out, int out_size, void* d_ws, size_t ws_size,
                              hipStream_t stream) {
    const float* query  = (const float*)d_in[0];
    const float* value  = (const float*)d_in[1];
    const float* refp   = (const float*)d_in[2];
    const float* W_off  = (const float*)d_in[3];
    const float* b_off  = (const float*)d_in[4];
    const float* W_attn = (const float*)d_in[5];
    const float* b_attn = (const float*)d_in[6];
    const float* W_val  = (const float*)d_in[7];
    const float* b_val  = (const float*)d_in[8];
    const float* W_out  = (const float*)d_in[9];
    const float* b_out  = (const float*)d_in[10];
    float* out = (float*)d_out;

    char* ws = (char*)d_ws;
    unsigned short* WTs    = (unsigned short*)(ws);                  // 128 KB
    unsigned short* v_ws   = (unsigned short*)(ws + 131072);         // 44.56 MB
    unsigned short* W1T    = (unsigned short*)(ws + 44695552);       // 96 KB
    unsigned short* WoT    = (unsigned short*)(ws + 44793856);       // 128 KB
    float*          logits = (float*)(ws + 44924928);                // 3 MB
    unsigned short* mid    = (unsigned short*)(ws + 47996928);       // 2 MB

    prep_kernel<<<CC, 256, 0, stream>>>(W_val, W_off, W_attn, W_out,
                                        WTs, W1T, WoT);
    valproj_mfma<<<(BB * NVV) / 64, 256, 0, stream>>>(value, WTs, b_val, v_ws);
    logits_mfma<<<NQT / 32, 256, 0, stream>>>(query, W1T, b_off, b_attn, logits);
    sample_kernel<<<NQT, 256, 0, stream>>>(logits, refp, v_ws, mid);
    out_mfma<<<NQT / 32, 256, 0, stream>>>(mid, WoT, b_out, out);
}